// Round 2
// baseline (10443.781 us; speedup 1.0000x reference)
//
#include <hip/hip_runtime.h>
#include <math.h>

#define Hn 512
#define En 256
#define Sn 32
#define Bn 1024
#define Tn 32
#define Vn 256
#define G3 1536
#define EHn 768

// fma4 as a FUNCTION, not a macro (R6 lesson: macro param `w` collides with `.w`).
__device__ __forceinline__ void fma4(float& acc, const float4 w, const float4 x) {
  acc = fmaf(w.x, x.x, acc);
  acc = fmaf(w.y, x.y, acc);
  acc = fmaf(w.z, x.z, acc);
  acc = fmaf(w.w, x.w, acc);
}

// ============ one-time weight transpose: W[gate][K] -> WT4[k4*G + g] ============
__global__ __launch_bounds__(256) void transpose_pack(const float* __restrict__ W,
                                                      float4* __restrict__ WT4,
                                                      int G, int K) {
  const int idx = blockIdx.x * blockDim.x + threadIdx.x;
  const int n = G * (K >> 2);
  if (idx >= n) return;
  const int k4 = idx / G, g = idx - k4 * G;
  WT4[idx] = *(const float4*)(W + (size_t)g * K + (k4 << 2));
}

// ============ kproj GEMM: C(M,N) = A(M,K) @ W(N,K)^T + bias ============
__global__ __launch_bounds__(256) void gemm_bias(const float* __restrict__ A,
                                                 const float* __restrict__ Wt,
                                                 const float* __restrict__ bias,
                                                 float* __restrict__ C,
                                                 int M, int N, int K) {
  __shared__ float As[16][68];
  __shared__ float Ws[16][68];
  const int bm = blockIdx.y * 64;
  const int bn = blockIdx.x * 64;
  const int tid = threadIdx.x;
  const int tx = tid & 15;
  const int ty = tid >> 4;
  const int kk = tid & 15;
  const int r0 = tid >> 4;
  float acc[4][4] = {};
  for (int k0 = 0; k0 < K; k0 += 16) {
#pragma unroll
    for (int i = 0; i < 4; ++i) {
      const int m = r0 + (i << 4);
      As[kk][m] = A[(size_t)(bm + m) * K + (k0 + kk)];
      Ws[kk][m] = Wt[(size_t)(bn + m) * K + (k0 + kk)];
    }
    __syncthreads();
#pragma unroll
    for (int k = 0; k < 16; ++k) {
      const float4 a4 = *(const float4*)&As[k][ty * 4];
      const float4 w4 = *(const float4*)&Ws[k][tx * 4];
      const float av[4] = {a4.x, a4.y, a4.z, a4.w};
      const float wv[4] = {w4.x, w4.y, w4.z, w4.w};
#pragma unroll
      for (int i = 0; i < 4; ++i)
#pragma unroll
        for (int j = 0; j < 4; ++j) acc[i][j] = fmaf(av[i], wv[j], acc[i][j]);
    }
    __syncthreads();
  }
#pragma unroll
  for (int i = 0; i < 4; ++i) {
    const size_t m = (size_t)bm + ty * 4 + i;
    float* crow = C + m * N + bn + tx * 4;
#pragma unroll
    for (int j = 0; j < 4; ++j) crow[j] = acc[i][j] + bias[bn + tx * 4 + j];
  }
}

// ============ Path A3: R=4, 1024-thread decoder, in-wave K-split ============
// R2 redesign: thread (jj = (tid&31)|((tid>>6)<<5), grp = (tid>>5)&1) owns
// output column jj with K-half grp; the K-split partner is lane tid^32 (SAME
// wave) so partial sums combine with one __shfl_xor(...,32) instead of the
// prt[16][1024] LDS round-trip + 2 barriers. Gate math row-splits by grp
// (2 rows per lane). fc argmax/logsumexp are wave-shuffle reductions.
// Barriers/step: 26 -> 11. LDS: 105KB dynamic -> ~43KB static.
// waves_per_eu(4,4): grid=256 blocks => always 1 block/CU (16 waves, 4/EU);
// without it the 43KB-LDS occupancy heuristic would cap VGPR for 12 waves/EU.

__device__ __forceinline__ void gru_pair(
    int jj, int grp,
    const float4* __restrict__ WihT, int Kih,
    const float4* __restrict__ WhhT,
    const float* __restrict__ x, int xstride,  // LDS [4][xstride]
    float* __restrict__ h,                     // LDS [4][Hn]
    const float* __restrict__ bih, const float* __restrict__ bhh) {
  float ar[4] = {}, az[4] = {}, ain[4] = {}, ahn[4] = {};
  {
    const int kc = (Kih >> 2) >> 1;
    const int k0 = grp * kc;
    const float4* w0 = WihT + jj + (size_t)k0 * G3;
    const float4* w1 = WihT + jj + 512 + (size_t)k0 * G3;
    const float4* w2 = WihT + jj + 1024 + (size_t)k0 * G3;
    for (int k4 = 0; k4 < kc; ++k4) {
      const float4 a = *w0; w0 += G3;
      const float4 b = *w1; w1 += G3;
      const float4 c = *w2; w2 += G3;
#pragma unroll
      for (int r = 0; r < 4; ++r) {
        const float4 xv = ((const float4*)(x + r * xstride))[k0 + k4];
        fma4(ar[r], a, xv);
        fma4(az[r], b, xv);
        fma4(ain[r], c, xv);
      }
    }
  }
  {
    const int kc = (Hn >> 2) >> 1;
    const int k0 = grp * kc;
    const float4* w0 = WhhT + jj + (size_t)k0 * G3;
    const float4* w1 = WhhT + jj + 512 + (size_t)k0 * G3;
    const float4* w2 = WhhT + jj + 1024 + (size_t)k0 * G3;
    for (int k4 = 0; k4 < kc; ++k4) {
      const float4 a = *w0; w0 += G3;
      const float4 b = *w1; w1 += G3;
      const float4 c = *w2; w2 += G3;
#pragma unroll
      for (int r = 0; r < 4; ++r) {
        const float4 xv = ((const float4*)(h + r * Hn))[k0 + k4];
        fma4(ar[r], a, xv);
        fma4(az[r], b, xv);
        fma4(ahn[r], c, xv);
      }
    }
  }
  // combine K-halves with the partner lane (same wave, lane^32)
#pragma unroll
  for (int r = 0; r < 4; ++r) {
    ar[r] += __shfl_xor(ar[r], 32);
    az[r] += __shfl_xor(az[r], 32);
    ain[r] += __shfl_xor(ain[r], 32);
    ahn[r] += __shfl_xor(ahn[r], 32);
  }
  // gate math: grp 0 -> rows 0,1 ; grp 1 -> rows 2,3 (static selects, rule #20)
  const float bir = bih[jj], biz = bih[jj + 512], bin = bih[jj + 1024];
  const float bhr = bhh[jj], bhz = bhh[jj + 512], bhn = bhh[jj + 1024];
  const int r2 = grp * 2;
  const float s0r = (grp ? ar[2] : ar[0]) + bir + bhr;
  const float s0z = (grp ? az[2] : az[0]) + biz + bhz;
  const float s0i = (grp ? ain[2] : ain[0]) + bin;
  const float s0h = (grp ? ahn[2] : ahn[0]) + bhn;
  const float s1r = (grp ? ar[3] : ar[1]) + bir + bhr;
  const float s1z = (grp ? az[3] : az[1]) + biz + bhz;
  const float s1i = (grp ? ain[3] : ain[1]) + bin;
  const float s1h = (grp ? ahn[3] : ahn[1]) + bhn;
  const float rg0 = 1.f / (1.f + expf(-s0r));
  const float zg0 = 1.f / (1.f + expf(-s0z));
  const float ng0 = tanhf(s0i + rg0 * s0h);
  const float rg1 = 1.f / (1.f + expf(-s1r));
  const float zg1 = 1.f / (1.f + expf(-s1z));
  const float ng1 = tanhf(s1i + rg1 * s1h);
  const float h0old = h[(r2 + 0) * Hn + jj];
  const float h1old = h[(r2 + 1) * Hn + jj];
  const float hn0 = (1.f - zg0) * ng0 + zg0 * h0old;
  const float hn1 = (1.f - zg1) * ng1 + zg1 * h1old;
  __syncthreads();  // all lanes done READING h before anyone writes it
  h[(r2 + 0) * Hn + jj] = hn0;
  h[(r2 + 1) * Hn + jj] = hn1;
  __syncthreads();
}

__global__ __launch_bounds__(1024) __attribute__((amdgpu_waves_per_eu(4, 4)))
void decoder_r4y(
    const float* __restrict__ state, const float* __restrict__ enc,
    const int* __restrict__ target, const float* __restrict__ emb,
    const float4* __restrict__ WaT, const float* __restrict__ bWa,
    const float* __restrict__ Va, const float* __restrict__ bVa,
    const float4* __restrict__ W0ihT, const float4* __restrict__ W0hhT,
    const float* __restrict__ bih0, const float* __restrict__ bhh0,
    const float4* __restrict__ W1ihT, const float4* __restrict__ W1hhT,
    const float* __restrict__ bih1, const float* __restrict__ bhh1,
    const float4* __restrict__ fcWT, const float* __restrict__ fcb,
    const float* __restrict__ kproj, float* __restrict__ out,
    float* __restrict__ wsloss, int* __restrict__ wscorrect) {
  __shared__ __attribute__((aligned(16))) float h0s[4 * Hn];
  __shared__ __attribute__((aligned(16))) float h1s[4 * Hn];
  __shared__ __attribute__((aligned(16))) float qps[4 * Hn];
  __shared__ __attribute__((aligned(16))) float gins[4 * EHn];
  __shared__ __attribute__((aligned(16))) float vas[Hn];
  __shared__ __attribute__((aligned(16))) float wrs[4 * Sn];
  __shared__ __attribute__((aligned(16))) float ep[1024];
  __shared__ float wred[16];
  __shared__ int wredi[16];
  __shared__ float mxv[4], lgt[4];
  __shared__ int tgv[4], tokb[4], mfs[4];

  const int tid = threadIdx.x;
  const int b0 = blockIdx.x * 4;
  const int jj = (tid & 31) | ((tid >> 6) << 5);  // 0..511, each twice
  const int grp = (tid >> 5) & 1;                 // K-half / row-group

  for (int i = tid; i < 4 * Hn; i += 1024) {
    const int r = i >> 9, j = i & 511;
    h0s[i] = state[(size_t)(b0 + r) * Hn + j];
    h1s[i] = state[(size_t)(Bn + b0 + r) * Hn + j];
  }
  if (tid < 512) vas[tid] = Va[tid];
  if (tid < 4) { tokb[tid] = 1; mfs[tid] = 1; }
  __syncthreads();

  float run_loss = 0.f;  // tid 0 only

  for (int t = 0; t < Tn; ++t) {
    // ---- qp = h1 @ Wa^T + bWa, in-wave K-split ----
    {
      const int kc = (Hn >> 2) >> 1;  // 64
      const int k0 = grp * kc;
      const float4* wp = WaT + jj + (size_t)k0 * Hn;
      float a0 = 0.f, a1 = 0.f, a2 = 0.f, a3 = 0.f;
      for (int k4 = 0; k4 < kc; ++k4) {
        const float4 w = *wp; wp += Hn;
        const float4 x0 = ((const float4*)(h1s))[k0 + k4];
        const float4 x1 = ((const float4*)(h1s + Hn))[k0 + k4];
        const float4 x2 = ((const float4*)(h1s + 2 * Hn))[k0 + k4];
        const float4 x3 = ((const float4*)(h1s + 3 * Hn))[k0 + k4];
        fma4(a0, w, x0); fma4(a1, w, x1); fma4(a2, w, x2); fma4(a3, w, x3);
      }
      a0 += __shfl_xor(a0, 32);
      a1 += __shfl_xor(a1, 32);
      a2 += __shfl_xor(a2, 32);
      a3 += __shfl_xor(a3, 32);
      const float bb = bWa[jj];
      if (!grp) {
        qps[jj] = a0 + bb;
        qps[Hn + jj] = a1 + bb;
      } else {
        qps[2 * Hn + jj] = a2 + bb;
        qps[3 * Hn + jj] = a3 + bb;
      }
    }
    __syncthreads();  // B1
    // ---- e: 8 threads per (r,s) pair; kproj streamed from global ----
    {
      const int p = tid >> 3, q = tid & 7;  // p = r*32+s
      const int r = p >> 5, s = p & 31;
      const float4* kp4 = (const float4*)(kproj + ((size_t)s * Bn + (b0 + r)) * Hn);
      const float4* qp4 = (const float4*)(qps + r * Hn);
      const float4* va4 = (const float4*)vas;
      float partial = 0.f;
      for (int i = 0; i < 16; ++i) {
        const int f = q + (i << 3);
        const float4 k4 = kp4[f], q4 = qp4[f], v4 = va4[f];
        partial += v4.x * tanhf(q4.x + k4.x);
        partial += v4.y * tanhf(q4.y + k4.y);
        partial += v4.z * tanhf(q4.z + k4.z);
        partial += v4.w * tanhf(q4.w + k4.w);
      }
      ep[tid] = partial;
    }
    __syncthreads();  // B2
    if (tid < 128) {
      float e = ep[tid * 8] + ep[tid * 8 + 1] + ep[tid * 8 + 2] + ep[tid * 8 + 3] +
                ep[tid * 8 + 4] + ep[tid * 8 + 5] + ep[tid * 8 + 6] + ep[tid * 8 + 7] +
                bVa[0];
      float m = e;
#pragma unroll
      for (int off = 16; off; off >>= 1) m = fmaxf(m, __shfl_xor(m, off));
      const float ex = expf(e - m);
      float ss = ex;
#pragma unroll
      for (int off = 16; off; off >>= 1) ss += __shfl_xor(ss, off);
      const float w = ex / ss;
      const int r = tid >> 5, s = tid & 31;
      wrs[tid] = w;
      out[(size_t)(Bn * Tn) + (size_t)t * (Bn * Sn) + (size_t)(b0 + r) * Sn + s] = w;
    }
    __syncthreads();  // B3
    // ---- context (2 rows per thread) + relu(emb[tok]) -> gin; preload target ----
    {
      const int h = tid & 511, rp = tid >> 9;  // rows 2rp, 2rp+1
      float c0 = 0.f, c1 = 0.f;
      const float* w0 = wrs + (2 * rp) * 32;
      const float* w1 = wrs + (2 * rp + 1) * 32;
      for (int s = 0; s < Sn; ++s) {
        const size_t base = ((size_t)s * Bn + b0 + 2 * rp) * Hn + h;
        c0 = fmaf(w0[s], enc[base], c0);
        c1 = fmaf(w1[s], enc[base + Hn], c1);
      }
      gins[(2 * rp) * EHn + En + h] = c0;
      gins[(2 * rp + 1) * EHn + En + h] = c1;
    }
    {
      const int r = tid >> 8, j = tid & 255;
      gins[r * EHn + j] = fmaxf(emb[(size_t)tokb[r] * En + j], 0.f);
    }
    if (tid < 4) tgv[tid] = target[(size_t)(b0 + tid) * Tn + t];
    __syncthreads();  // B4
    // ---- GRU layers (in-wave K-split; 2 barriers each) ----
    gru_pair(jj, grp, W0ihT, EHn, W0hhT, gins, EHn, h0s, bih0, bhh0);  // B5,B6
    gru_pair(jj, grp, W1ihT, Hn, W1hhT, h0s, Hn, h1s, bih1, bhh1);     // B7,B8
    // ---- fc: one (v, row) per thread; logit stays in a register ----
    const int v = tid & 255, rr = tid >> 8;
    float l;
    {
      const float4* wp = fcWT + v;
      const float4* xr = (const float4*)(h1s + rr * Hn);
      float acc = 0.f;
      for (int k4 = 0; k4 < (Hn >> 2); ++k4) {
        const float4 w = *wp; wp += Vn;
        fma4(acc, w, xr[k4]);
      }
      l = acc + fcb[v];
    }
    if (v == tgv[rr]) lgt[rr] = l;  // target logit for the loss
    // wave-level argmax (first-max tie-break), 4 waves per row
    {
      float m = l;
      int mi = v;
#pragma unroll
      for (int off = 32; off; off >>= 1) {
        const float om = __shfl_xor(m, off);
        const int oi = __shfl_xor(mi, off);
        if (om > m || (om == m && oi < mi)) { m = om; mi = oi; }
      }
      if ((tid & 63) == 0) {
        wred[tid >> 6] = m;
        wredi[tid >> 6] = mi;
      }
    }
    __syncthreads();  // B9
    int am_r = 0;  // valid only in tid<4
    if (tid < 4) {
      float bm = wred[4 * tid];
      int bi = wredi[4 * tid];
#pragma unroll
      for (int q = 1; q < 4; ++q) {
        const float o = wred[4 * tid + q];
        const int oi = wredi[4 * tid + q];
        if (o > bm || (o == bm && oi < bi)) { bm = o; bi = oi; }
      }
      mxv[tid] = bm;
      am_r = bi;
    }
    __syncthreads();  // B10
    {
      float ex = expf(l - mxv[rr]);
#pragma unroll
      for (int off = 32; off; off >>= 1) ex += __shfl_xor(ex, off);
      if ((tid & 63) == 0) wred[tid >> 6] = ex;
    }
    __syncthreads();  // B11
    if (tid < 4) {
      tokb[tid] = am_r;
      if (am_r != tgv[tid]) mfs[tid] = 0;
      out[(size_t)(b0 + tid) * Tn + t] = (float)am_r;
    }
    if (tid == 0) {
#pragma unroll
      for (int r = 0; r < 4; ++r) {
        const float s = wred[4 * r] + wred[4 * r + 1] + wred[4 * r + 2] + wred[4 * r + 3];
        run_loss += -(lgt[r] - mxv[r] - logf(s)) * (1.f / 1024.f);
      }
    }
    // no trailing barrier needed: next-step hazards are covered by B1..B11
    // (writers of wred/lgt/mxv next step sit behind B1/B8/B9, which tid0 and
    //  tid<4 must also reach; tokb readers sit behind next B3).
  }

  __syncthreads();
  if (tid == 0) {
    atomicAdd(wsloss, run_loss);
    atomicAdd(wscorrect, mfs[0] + mfs[1] + mfs[2] + mfs[3]);
  }
}

// ============ Path A fallback: R5-verified decoder (uncoalesced weights) ========
__device__ __forceinline__ void gru_layer4(int j, const float* __restrict__ x,
                                           int xstride, int K,
                                           float* __restrict__ h,
                                           const float* __restrict__ Wih,
                                           const float* __restrict__ Whh,
                                           const float* __restrict__ bih,
                                           const float* __restrict__ bhh) {
  float ai0[4] = {}, ai1[4] = {}, ai2[4] = {};
  {
    const float4* w0 = (const float4*)(Wih + (size_t)j * K);
    const float4* w1 = (const float4*)(Wih + (size_t)(j + 512) * K);
    const float4* w2 = (const float4*)(Wih + (size_t)(j + 1024) * K);
    for (int i = 0; i < K / 4; ++i) {
      const float4 a = w0[i], b = w1[i], c = w2[i];
#pragma unroll
      for (int r = 0; r < 4; ++r) {
        const float4 xv = ((const float4*)(x + r * xstride))[i];
        fma4(ai0[r], a, xv); fma4(ai1[r], b, xv); fma4(ai2[r], c, xv);
      }
    }
  }
  float ah0[4] = {}, ah1[4] = {}, ah2[4] = {};
  {
    const float4* w0 = (const float4*)(Whh + (size_t)j * Hn);
    const float4* w1 = (const float4*)(Whh + (size_t)(j + 512) * Hn);
    const float4* w2 = (const float4*)(Whh + (size_t)(j + 1024) * Hn);
    for (int i = 0; i < Hn / 4; ++i) {
      const float4 a = w0[i], b = w1[i], c = w2[i];
#pragma unroll
      for (int r = 0; r < 4; ++r) {
        const float4 xv = ((const float4*)(h + r * Hn))[i];
        fma4(ah0[r], a, xv); fma4(ah1[r], b, xv); fma4(ah2[r], c, xv);
      }
    }
  }
  const float bi0 = bih[j], bi1 = bih[j + 512], bi2 = bih[j + 1024];
  const float bh0 = bhh[j], bh1 = bhh[j + 512], bh2 = bhh[j + 1024];
  float hn[4];
#pragma unroll
  for (int r = 0; r < 4; ++r) {
    const float ir = ai0[r] + bi0, iz = ai1[r] + bi1, in_ = ai2[r] + bi2;
    const float hr = ah0[r] + bh0, hz = ah1[r] + bh1, hnn = ah2[r] + bh2;
    const float rg = 1.f / (1.f + expf(-(ir + hr)));
    const float zg = 1.f / (1.f + expf(-(iz + hz)));
    const float ng = tanhf(in_ + rg * hnn);
    hn[r] = (1.f - zg) * ng + zg * h[r * Hn + j];
  }
  __syncthreads();
#pragma unroll
  for (int r = 0; r < 4; ++r) h[r * Hn + j] = hn[r];
  __syncthreads();
}

__global__ __launch_bounds__(512, 1) void decoder_r4(
    const float* __restrict__ state, const float* __restrict__ enc,
    const int* __restrict__ target, const float* __restrict__ emb,
    const float* __restrict__ Wa, const float* __restrict__ bWa,
    const float* __restrict__ Va, const float* __restrict__ bVa,
    const float* __restrict__ Wih0, const float* __restrict__ Whh0,
    const float* __restrict__ bih0, const float* __restrict__ bhh0,
    const float* __restrict__ Wih1, const float* __restrict__ Whh1,
    const float* __restrict__ bih1, const float* __restrict__ bhh1,
    const float* __restrict__ fcW, const float* __restrict__ fcb,
    const float* __restrict__ kproj, float* __restrict__ out,
    float* __restrict__ wsloss, int* __restrict__ wscorrect) {
  __shared__ float h0s[4 * Hn], h1s[4 * Hn], qps[4 * Hn], gins[4 * EHn], vas[Hn];
  __shared__ float red[1024], lg[1024];
  __shared__ int ridx[1024];
  __shared__ float wrs[4 * Sn];
  __shared__ float mxv[4], lzv[4], llv[4];
  __shared__ int amv[4], tgv[4], tokb[4], mfs[4];

  const int tid = threadIdx.x;
  const int b0 = blockIdx.x * 4;

  for (int i = tid; i < 4 * Hn; i += 512) {
    const int r = i >> 9, j = i & 511;
    h0s[i] = state[(size_t)(b0 + r) * Hn + j];
    h1s[i] = state[(size_t)(Bn + b0 + r) * Hn + j];
  }
  vas[tid] = Va[tid];
  if (tid < 4) { tokb[tid] = 1; mfs[tid] = 1; llv[tid] = 0.f; }
  __syncthreads();

  float run_loss = 0.f;

  for (int t = 0; t < Tn; ++t) {
    {
      const int h = tid;
      const float4* w4 = (const float4*)(Wa + (size_t)h * Hn);
      float a0 = 0.f, a1 = 0.f, a2 = 0.f, a3 = 0.f;
      for (int i = 0; i < Hn / 4; ++i) {
        const float4 w = w4[i];
        const float4 x0 = ((const float4*)(h1s))[i];
        const float4 x1 = ((const float4*)(h1s + Hn))[i];
        const float4 x2 = ((const float4*)(h1s + 2 * Hn))[i];
        const float4 x3 = ((const float4*)(h1s + 3 * Hn))[i];
        fma4(a0, w, x0); fma4(a1, w, x1); fma4(a2, w, x2); fma4(a3, w, x3);
      }
      const float bb = bWa[h];
      qps[h] = a0 + bb; qps[Hn + h] = a1 + bb;
      qps[2 * Hn + h] = a2 + bb; qps[3 * Hn + h] = a3 + bb;
    }
    __syncthreads();
    {
      const int p = tid >> 2, q = tid & 3;
      const int r = p >> 5, s = p & 31;
      const float4* kp4 = (const float4*)(kproj + ((size_t)s * Bn + (b0 + r)) * Hn);
      const float4* qp4 = (const float4*)(qps + r * Hn);
      const float4* va4 = (const float4*)vas;
      float partial = 0.f;
      for (int i = 0; i < 32; ++i) {
        const int f = q + (i << 2);
        const float4 k4 = kp4[f], q4 = qp4[f], v4 = va4[f];
        partial += v4.x * tanhf(q4.x + k4.x);
        partial += v4.y * tanhf(q4.y + k4.y);
        partial += v4.z * tanhf(q4.z + k4.z);
        partial += v4.w * tanhf(q4.w + k4.w);
      }
      red[tid] = partial;
    }
    __syncthreads();
    if (tid < 128) {
      float e = red[tid * 4] + red[tid * 4 + 1] + red[tid * 4 + 2] + red[tid * 4 + 3] + bVa[0];
      float m = e;
#pragma unroll
      for (int off = 16; off; off >>= 1) m = fmaxf(m, __shfl_xor(m, off));
      const float ex = expf(e - m);
      float ss = ex;
#pragma unroll
      for (int off = 16; off; off >>= 1) ss += __shfl_xor(ss, off);
      const float w = ex / ss;
      const int r = tid >> 5, s = tid & 31;
      wrs[tid] = w;
      out[(size_t)(Bn * Tn) + (size_t)t * (Bn * Sn) + (size_t)(b0 + r) * Sn + s] = w;
    }
    __syncthreads();
    {
      const int h = tid;
      float c0 = 0.f, c1 = 0.f, c2 = 0.f, c3 = 0.f;
      for (int s = 0; s < Sn; ++s) {
        const size_t base = ((size_t)s * Bn + b0) * Hn + h;
        c0 = fmaf(wrs[s], enc[base], c0);
        c1 = fmaf(wrs[32 + s], enc[base + Hn], c1);
        c2 = fmaf(wrs[64 + s], enc[base + 2 * Hn], c2);
        c3 = fmaf(wrs[96 + s], enc[base + 3 * Hn], c3);
      }
      gins[En + h] = c0; gins[EHn + En + h] = c1;
      gins[2 * EHn + En + h] = c2; gins[3 * EHn + En + h] = c3;
    }
    for (int i = tid; i < 4 * En; i += 512) {
      const int r = i >> 8, j = i & 255;
      gins[r * EHn + j] = fmaxf(emb[(size_t)tokb[r] * En + j], 0.f);
    }
    __syncthreads();
    gru_layer4(tid, gins, EHn, EHn, h0s, Wih0, Whh0, bih0, bhh0);
    gru_layer4(tid, h0s, Hn, Hn, h1s, Wih1, Whh1, bih1, bhh1);
    {
      const int v = tid & 255;
      const int rA = tid >> 8, rB = rA + 2;
      const float4* w4 = (const float4*)(fcW + (size_t)v * Hn);
      const float4* xA = (const float4*)(h1s + rA * Hn);
      const float4* xB = (const float4*)(h1s + rB * Hn);
      float aA = 0.f, aB = 0.f;
      for (int i = 0; i < Hn / 4; ++i) {
        const float4 w = w4[i];
        const float4 a = xA[i], b = xB[i];
        fma4(aA, w, a); fma4(aB, w, b);
      }
      const float fb = fcb[v];
      const float lA = aA + fb, lB = aB + fb;
      lg[rA * 256 + v] = lA; red[rA * 256 + v] = lA; ridx[rA * 256 + v] = v;
      lg[rB * 256 + v] = lB; red[rB * 256 + v] = lB; ridx[rB * 256 + v] = v;
    }
    __syncthreads();
    for (int off = 128; off; off >>= 1) {
#pragma unroll
      for (int half = 0; half < 2; ++half) {
        const int u = tid + half * 512;
        if ((u & 255) < off) {
          const int u2 = u + off;
          const float o = red[u2]; const int oi = ridx[u2];
          if (o > red[u] || (o == red[u] && oi < ridx[u])) { red[u] = o; ridx[u] = oi; }
        }
      }
      __syncthreads();
    }
    if (tid < 4) {
      mxv[tid] = red[tid * 256];
      amv[tid] = ridx[tid * 256];
      tgv[tid] = target[(size_t)(b0 + tid) * Tn + t];
    }
    __syncthreads();
#pragma unroll
    for (int half = 0; half < 2; ++half) {
      const int u = tid + half * 512;
      red[u] = expf(lg[u] - mxv[u >> 8]);
    }
    __syncthreads();
    for (int off = 128; off; off >>= 1) {
#pragma unroll
      for (int half = 0; half < 2; ++half) {
        const int u = tid + half * 512;
        if ((u & 255) < off) red[u] += red[u + off];
      }
      __syncthreads();
    }
    if (tid < 4) {
      const int r = tid;
      lzv[r] = logf(red[r * 256]);
      tokb[r] = amv[r];
      if (amv[r] != tgv[r]) mfs[r] = 0;
      out[(size_t)(b0 + r) * Tn + t] = (float)amv[r];
    }
    __syncthreads();
#pragma unroll
    for (int half = 0; half < 2; ++half) {
      const int u = tid + half * 512;
      const int r = u >> 8, v = u & 255;
      if (v == tgv[r]) llv[r] = -(lg[u] - mxv[r] - lzv[r]) * (1.f / 1024.f);
    }
    __syncthreads();
    if (tid == 0) run_loss += llv[0] + llv[1] + llv[2] + llv[3];
    __syncthreads();
  }

  if (tid == 0) {
    atomicAdd(wsloss, run_loss);
    atomicAdd(wscorrect, mfs[0] + mfs[1] + mfs[2] + mfs[3]);
  }
}

// ============ common epilogue ============
__global__ void ws_init(float* wsloss, int* wscorrect) {
  wsloss[0] = 0.f;
  wscorrect[0] = 0;
}

__global__ void finisher(const float* __restrict__ wsloss,
                         const int* __restrict__ wscorrect, float* __restrict__ out) {
  const size_t base = (size_t)Bn * Tn + (size_t)Tn * Bn * Sn;
  out[base] = wsloss[0];
  out[base + 1] = (float)wscorrect[0];
}

extern "C" void kernel_launch(void* const* d_in, const int* in_sizes, int n_in,
                              void* d_out, int out_size, void* d_ws, size_t ws_size,
                              hipStream_t stream) {
  const float* state = (const float*)d_in[0];
  const float* enc = (const float*)d_in[1];
  const int* target = (const int*)d_in[2];
  const float* emb = (const float*)d_in[3];
  const float* Wa = (const float*)d_in[4];
  const float* bWa = (const float*)d_in[5];
  const float* Ua = (const float*)d_in[6];
  const float* bUa = (const float*)d_in[7];
  const float* Va = (const float*)d_in[8];
  const float* bVa = (const float*)d_in[9];
  const float* Wih0 = (const float*)d_in[10];
  const float* Whh0 = (const float*)d_in[11];
  const float* bih0 = (const float*)d_in[12];
  const float* bhh0 = (const float*)d_in[13];
  const float* Wih1 = (const float*)d_in[14];
  const float* Whh1 = (const float*)d_in[15];
  const float* bih1 = (const float*)d_in[16];
  const float* bhh1 = (const float*)d_in[17];
  const float* fcW = (const float*)d_in[18];
  const float* fcb = (const float*)d_in[19];
  float* out = (float*)d_out;

  const size_t KPROJ_FLOATS = (size_t)Sn * Bn * Hn;  // 64 MB

  const size_t N0IH = (size_t)G3 * (EHn / 4);
  const size_t NHH = (size_t)G3 * (Hn / 4);
  const size_t NWA = (size_t)Hn * (Hn / 4);
  const size_t NFC = (size_t)Vn * (Hn / 4);
  const size_t WT_TOTAL = N0IH + 3 * NHH + NWA + NFC;  // 15 MB
  const size_t NEED_A2 = WT_TOTAL * 16 + KPROJ_FLOATS * 4 + 256;

  if (ws_size >= NEED_A2) {
    float4* W0ihT = (float4*)d_ws;
    float4* W0hhT = W0ihT + N0IH;
    float4* W1ihT = W0hhT + NHH;
    float4* W1hhT = W1ihT + NHH;
    float4* WaT = W1hhT + NHH;
    float4* fcWT = WaT + NWA;
    float* kproj = (float*)(fcWT + NFC);
    float* wsloss = kproj + KPROJ_FLOATS;
    int* wscorrect = (int*)(wsloss + 1);

    ws_init<<<1, 1, 0, stream>>>(wsloss, wscorrect);
    transpose_pack<<<(int)((N0IH + 255) / 256), 256, 0, stream>>>(Wih0, W0ihT, G3, EHn);
    transpose_pack<<<(int)((NHH + 255) / 256), 256, 0, stream>>>(Whh0, W0hhT, G3, Hn);
    transpose_pack<<<(int)((NHH + 255) / 256), 256, 0, stream>>>(Wih1, W1ihT, G3, Hn);
    transpose_pack<<<(int)((NHH + 255) / 256), 256, 0, stream>>>(Whh1, W1hhT, G3, Hn);
    transpose_pack<<<(int)((NWA + 255) / 256), 256, 0, stream>>>(Wa, WaT, Hn, Hn);
    transpose_pack<<<(int)((NFC + 255) / 256), 256, 0, stream>>>(fcW, fcWT, Vn, Hn);
    gemm_bias<<<dim3(Hn / 64, (Sn * Bn) / 64), 256, 0, stream>>>(
        enc, Ua, bUa, kproj, Sn * Bn, Hn, Hn);
    decoder_r4y<<<Bn / 4, 1024, 0, stream>>>(
        state, enc, target, emb, WaT, bWa, Va, bVa, W0ihT, W0hhT, bih0, bhh0,
        W1ihT, W1hhT, bih1, bhh1, fcWT, fcb, kproj, out, wsloss, wscorrect);
    finisher<<<1, 1, 0, stream>>>(wsloss, wscorrect, out);
  } else {
    float* kproj = (float*)d_ws;
    float* wsloss = (float*)d_ws + KPROJ_FLOATS;
    int* wscorrect = (int*)((float*)d_ws + KPROJ_FLOATS + 1);
    ws_init<<<1, 1, 0, stream>>>(wsloss, wscorrect);
    gemm_bias<<<dim3(Hn / 64, (Sn * Bn) / 64), 256, 0, stream>>>(
        enc, Ua, bUa, kproj, Sn * Bn, Hn, Hn);
    decoder_r4<<<Bn / 4, 512, 0, stream>>>(
        state, enc, target, emb, Wa, bWa, Va, bVa, Wih0, Whh0, bih0, bhh0,
        Wih1, Whh1, bih1, bhh1, fcW, fcb, kproj, out, wsloss, wscorrect);
    finisher<<<1, 1, 0, stream>>>(wsloss, wscorrect, out);
  }
}

// Round 3
// 9954.934 us; speedup vs baseline: 1.0491x; 1.0491x over previous
//
#include <hip/hip_runtime.h>
#include <math.h>

#define Hn 512
#define En 256
#define Sn 32
#define Bn 1024
#define Tn 32
#define Vn 256
#define G3 1536
#define EHn 768

// fma4 as a FUNCTION, not a macro (R6 lesson: macro param `w` collides with `.w`).
__device__ __forceinline__ void fma4(float& acc, const float4 w, const float4 x) {
  acc = fmaf(w.x, x.x, acc);
  acc = fmaf(w.y, x.y, acc);
  acc = fmaf(w.z, x.z, acc);
  acc = fmaf(w.w, x.w, acc);
}

// ============ one-time weight transpose: W[gate][K] -> WT4[k4*G + g] ============
__global__ __launch_bounds__(256) void transpose_pack(const float* __restrict__ W,
                                                      float4* __restrict__ WT4,
                                                      int G, int K) {
  const int idx = blockIdx.x * blockDim.x + threadIdx.x;
  const int n = G * (K >> 2);
  if (idx >= n) return;
  const int k4 = idx / G, g = idx - k4 * G;
  WT4[idx] = *(const float4*)(W + (size_t)g * K + (k4 << 2));
}

// ============ kproj GEMM: C(M,N) = A(M,K) @ W(N,K)^T + bias ============
__global__ __launch_bounds__(256) void gemm_bias(const float* __restrict__ A,
                                                 const float* __restrict__ Wt,
                                                 const float* __restrict__ bias,
                                                 float* __restrict__ C,
                                                 int M, int N, int K) {
  __shared__ float As[16][68];
  __shared__ float Ws[16][68];
  const int bm = blockIdx.y * 64;
  const int bn = blockIdx.x * 64;
  const int tid = threadIdx.x;
  const int tx = tid & 15;
  const int ty = tid >> 4;
  const int kk = tid & 15;
  const int r0 = tid >> 4;
  float acc[4][4] = {};
  for (int k0 = 0; k0 < K; k0 += 16) {
#pragma unroll
    for (int i = 0; i < 4; ++i) {
      const int m = r0 + (i << 4);
      As[kk][m] = A[(size_t)(bm + m) * K + (k0 + kk)];
      Ws[kk][m] = Wt[(size_t)(bn + m) * K + (k0 + kk)];
    }
    __syncthreads();
#pragma unroll
    for (int k = 0; k < 16; ++k) {
      const float4 a4 = *(const float4*)&As[k][ty * 4];
      const float4 w4 = *(const float4*)&Ws[k][tx * 4];
      const float av[4] = {a4.x, a4.y, a4.z, a4.w};
      const float wv[4] = {w4.x, w4.y, w4.z, w4.w};
#pragma unroll
      for (int i = 0; i < 4; ++i)
#pragma unroll
        for (int j = 0; j < 4; ++j) acc[i][j] = fmaf(av[i], wv[j], acc[i][j]);
    }
    __syncthreads();
  }
#pragma unroll
  for (int i = 0; i < 4; ++i) {
    const size_t m = (size_t)bm + ty * 4 + i;
    float* crow = C + m * N + bn + tx * 4;
#pragma unroll
    for (int j = 0; j < 4; ++j) crow[j] = acc[i][j] + bias[bn + tx * 4 + j];
  }
}

// ============ Path A3: R=4, 1024-thread decoder, in-wave K-split ============
// R2: in-wave K-split (partner lane tid^32), 11 barriers/step, 44KB LDS.
// R3: latency-bound diagnosis (VALUBusy 40%, L2 36%, HBM 11%, nothing >50%).
// All hot K-loops get compile-time trip counts + unroll-by-2/4 so >=2 load
// groups are in flight; waves_per_eu(4,4) gives the 128-VGPR budget to hold
// them. No numerics/layout/sync changes vs R2.

template <int KCI, int KCH>
__device__ __forceinline__ void gru_pair(
    int jj, int grp,
    const float4* __restrict__ WihT,
    const float4* __restrict__ WhhT,
    const float* __restrict__ x, int xstride,  // LDS [4][xstride]
    float* __restrict__ h,                     // LDS [4][Hn]
    const float* __restrict__ bih, const float* __restrict__ bhh) {
  float ar[4] = {}, az[4] = {}, ain[4] = {}, ahn[4] = {};
  {
    const int k0 = grp * KCI;
    const float4* w0 = WihT + jj + (size_t)k0 * G3;
    const float4* w1 = WihT + jj + 512 + (size_t)k0 * G3;
    const float4* w2 = WihT + jj + 1024 + (size_t)k0 * G3;
    const float4* xp = (const float4*)(x)+k0;
    for (int k4 = 0; k4 < KCI; k4 += 2) {
#pragma unroll
      for (int u = 0; u < 2; ++u) {
        const float4 a = w0[(size_t)(k4 + u) * G3];
        const float4 b = w1[(size_t)(k4 + u) * G3];
        const float4 c = w2[(size_t)(k4 + u) * G3];
#pragma unroll
        for (int r = 0; r < 4; ++r) {
          const float4 xv = ((const float4*)(x + r * xstride))[k0 + k4 + u];
          fma4(ar[r], a, xv);
          fma4(az[r], b, xv);
          fma4(ain[r], c, xv);
        }
      }
    }
    (void)xp;
  }
  {
    const int k0 = grp * KCH;
    const float4* w0 = WhhT + jj + (size_t)k0 * G3;
    const float4* w1 = WhhT + jj + 512 + (size_t)k0 * G3;
    const float4* w2 = WhhT + jj + 1024 + (size_t)k0 * G3;
    for (int k4 = 0; k4 < KCH; k4 += 2) {
#pragma unroll
      for (int u = 0; u < 2; ++u) {
        const float4 a = w0[(size_t)(k4 + u) * G3];
        const float4 b = w1[(size_t)(k4 + u) * G3];
        const float4 c = w2[(size_t)(k4 + u) * G3];
#pragma unroll
        for (int r = 0; r < 4; ++r) {
          const float4 xv = ((const float4*)(h + r * Hn))[k0 + k4 + u];
          fma4(ar[r], a, xv);
          fma4(az[r], b, xv);
          fma4(ahn[r], c, xv);
        }
      }
    }
  }
  // combine K-halves with the partner lane (same wave, lane^32)
#pragma unroll
  for (int r = 0; r < 4; ++r) {
    ar[r] += __shfl_xor(ar[r], 32);
    az[r] += __shfl_xor(az[r], 32);
    ain[r] += __shfl_xor(ain[r], 32);
    ahn[r] += __shfl_xor(ahn[r], 32);
  }
  // gate math: grp 0 -> rows 0,1 ; grp 1 -> rows 2,3 (static selects, rule #20)
  const float bir = bih[jj], biz = bih[jj + 512], bin = bih[jj + 1024];
  const float bhr = bhh[jj], bhz = bhh[jj + 512], bhn = bhh[jj + 1024];
  const int r2 = grp * 2;
  const float s0r = (grp ? ar[2] : ar[0]) + bir + bhr;
  const float s0z = (grp ? az[2] : az[0]) + biz + bhz;
  const float s0i = (grp ? ain[2] : ain[0]) + bin;
  const float s0h = (grp ? ahn[2] : ahn[0]) + bhn;
  const float s1r = (grp ? ar[3] : ar[1]) + bir + bhr;
  const float s1z = (grp ? az[3] : az[1]) + biz + bhz;
  const float s1i = (grp ? ain[3] : ain[1]) + bin;
  const float s1h = (grp ? ahn[3] : ahn[1]) + bhn;
  const float rg0 = 1.f / (1.f + expf(-s0r));
  const float zg0 = 1.f / (1.f + expf(-s0z));
  const float ng0 = tanhf(s0i + rg0 * s0h);
  const float rg1 = 1.f / (1.f + expf(-s1r));
  const float zg1 = 1.f / (1.f + expf(-s1z));
  const float ng1 = tanhf(s1i + rg1 * s1h);
  const float h0old = h[(r2 + 0) * Hn + jj];
  const float h1old = h[(r2 + 1) * Hn + jj];
  const float hn0 = (1.f - zg0) * ng0 + zg0 * h0old;
  const float hn1 = (1.f - zg1) * ng1 + zg1 * h1old;
  __syncthreads();  // all lanes done READING h before anyone writes it
  h[(r2 + 0) * Hn + jj] = hn0;
  h[(r2 + 1) * Hn + jj] = hn1;
  __syncthreads();
}

__global__ __launch_bounds__(1024) __attribute__((amdgpu_waves_per_eu(4, 4)))
void decoder_r4y(
    const float* __restrict__ state, const float* __restrict__ enc,
    const int* __restrict__ target, const float* __restrict__ emb,
    const float4* __restrict__ WaT, const float* __restrict__ bWa,
    const float* __restrict__ Va, const float* __restrict__ bVa,
    const float4* __restrict__ W0ihT, const float4* __restrict__ W0hhT,
    const float* __restrict__ bih0, const float* __restrict__ bhh0,
    const float4* __restrict__ W1ihT, const float4* __restrict__ W1hhT,
    const float* __restrict__ bih1, const float* __restrict__ bhh1,
    const float4* __restrict__ fcWT, const float* __restrict__ fcb,
    const float* __restrict__ kproj, float* __restrict__ out,
    float* __restrict__ wsloss, int* __restrict__ wscorrect) {
  __shared__ __attribute__((aligned(16))) float h0s[4 * Hn];
  __shared__ __attribute__((aligned(16))) float h1s[4 * Hn];
  __shared__ __attribute__((aligned(16))) float qps[4 * Hn];
  __shared__ __attribute__((aligned(16))) float gins[4 * EHn];
  __shared__ __attribute__((aligned(16))) float vas[Hn];
  __shared__ __attribute__((aligned(16))) float wrs[4 * Sn];
  __shared__ __attribute__((aligned(16))) float ep[1024];
  __shared__ float wred[16];
  __shared__ int wredi[16];
  __shared__ float mxv[4], lgt[4];
  __shared__ int tgv[4], tokb[4], mfs[4];

  const int tid = threadIdx.x;
  const int b0 = blockIdx.x * 4;
  const int jj = (tid & 31) | ((tid >> 6) << 5);  // 0..511, each twice
  const int grp = (tid >> 5) & 1;                 // K-half / row-group

  for (int i = tid; i < 4 * Hn; i += 1024) {
    const int r = i >> 9, j = i & 511;
    h0s[i] = state[(size_t)(b0 + r) * Hn + j];
    h1s[i] = state[(size_t)(Bn + b0 + r) * Hn + j];
  }
  if (tid < 512) vas[tid] = Va[tid];
  if (tid < 4) { tokb[tid] = 1; mfs[tid] = 1; }
  __syncthreads();

  float run_loss = 0.f;  // tid 0 only

  for (int t = 0; t < Tn; ++t) {
    // ---- qp = h1 @ Wa^T + bWa, in-wave K-split ----
    {
      const int kc = (Hn >> 2) >> 1;  // 64
      const int k0 = grp * kc;
      const float4* wp = WaT + jj + (size_t)k0 * Hn;
      float a0 = 0.f, a1 = 0.f, a2 = 0.f, a3 = 0.f;
      for (int k4 = 0; k4 < 64; k4 += 2) {
#pragma unroll
        for (int u = 0; u < 2; ++u) {
          const float4 w = wp[(size_t)(k4 + u) * Hn];
          const float4 x0 = ((const float4*)(h1s))[k0 + k4 + u];
          const float4 x1 = ((const float4*)(h1s + Hn))[k0 + k4 + u];
          const float4 x2 = ((const float4*)(h1s + 2 * Hn))[k0 + k4 + u];
          const float4 x3 = ((const float4*)(h1s + 3 * Hn))[k0 + k4 + u];
          fma4(a0, w, x0); fma4(a1, w, x1); fma4(a2, w, x2); fma4(a3, w, x3);
        }
      }
      a0 += __shfl_xor(a0, 32);
      a1 += __shfl_xor(a1, 32);
      a2 += __shfl_xor(a2, 32);
      a3 += __shfl_xor(a3, 32);
      const float bb = bWa[jj];
      if (!grp) {
        qps[jj] = a0 + bb;
        qps[Hn + jj] = a1 + bb;
      } else {
        qps[2 * Hn + jj] = a2 + bb;
        qps[3 * Hn + jj] = a3 + bb;
      }
    }
    __syncthreads();  // B1
    // ---- e: 8 threads per (r,s) pair; kproj streamed from global ----
    {
      const int p = tid >> 3, q = tid & 7;  // p = r*32+s
      const int r = p >> 5, s = p & 31;
      const float4* kp4 = (const float4*)(kproj + ((size_t)s * Bn + (b0 + r)) * Hn);
      const float4* qp4 = (const float4*)(qps + r * Hn);
      const float4* va4 = (const float4*)vas;
      float partial = 0.f;
      for (int i = 0; i < 16; i += 2) {
#pragma unroll
        for (int u = 0; u < 2; ++u) {
          const int f = q + ((i + u) << 3);
          const float4 k4 = kp4[f], q4 = qp4[f], v4 = va4[f];
          partial += v4.x * tanhf(q4.x + k4.x);
          partial += v4.y * tanhf(q4.y + k4.y);
          partial += v4.z * tanhf(q4.z + k4.z);
          partial += v4.w * tanhf(q4.w + k4.w);
        }
      }
      ep[tid] = partial;
    }
    __syncthreads();  // B2
    if (tid < 128) {
      float e = ep[tid * 8] + ep[tid * 8 + 1] + ep[tid * 8 + 2] + ep[tid * 8 + 3] +
                ep[tid * 8 + 4] + ep[tid * 8 + 5] + ep[tid * 8 + 6] + ep[tid * 8 + 7] +
                bVa[0];
      float m = e;
#pragma unroll
      for (int off = 16; off; off >>= 1) m = fmaxf(m, __shfl_xor(m, off));
      const float ex = expf(e - m);
      float ss = ex;
#pragma unroll
      for (int off = 16; off; off >>= 1) ss += __shfl_xor(ss, off);
      const float w = ex / ss;
      const int r = tid >> 5, s = tid & 31;
      wrs[tid] = w;
      out[(size_t)(Bn * Tn) + (size_t)t * (Bn * Sn) + (size_t)(b0 + r) * Sn + s] = w;
    }
    __syncthreads();  // B3
    // ---- context (2 rows per thread) + relu(emb[tok]) -> gin; preload target ----
    {
      const int h = tid & 511, rp = tid >> 9;  // rows 2rp, 2rp+1
      float c0 = 0.f, c1 = 0.f;
      const float* w0 = wrs + (2 * rp) * 32;
      const float* w1 = wrs + (2 * rp + 1) * 32;
#pragma unroll 4
      for (int s = 0; s < Sn; ++s) {
        const size_t base = ((size_t)s * Bn + b0 + 2 * rp) * Hn + h;
        c0 = fmaf(w0[s], enc[base], c0);
        c1 = fmaf(w1[s], enc[base + Hn], c1);
      }
      gins[(2 * rp) * EHn + En + h] = c0;
      gins[(2 * rp + 1) * EHn + En + h] = c1;
    }
    {
      const int r = tid >> 8, j = tid & 255;
      gins[r * EHn + j] = fmaxf(emb[(size_t)tokb[r] * En + j], 0.f);
    }
    if (tid < 4) tgv[tid] = target[(size_t)(b0 + tid) * Tn + t];
    __syncthreads();  // B4
    // ---- GRU layers (in-wave K-split; 2 barriers each) ----
    gru_pair<96, 64>(jj, grp, W0ihT, W0hhT, gins, EHn, h0s, bih0, bhh0);  // B5,B6
    gru_pair<64, 64>(jj, grp, W1ihT, W1hhT, h0s, Hn, h1s, bih1, bhh1);    // B7,B8
    // ---- fc: one (v, row) per thread; logit stays in a register ----
    const int v = tid & 255, rr = tid >> 8;
    float l;
    {
      const float4* wp = fcWT + v;
      const float4* xr = (const float4*)(h1s + rr * Hn);
      float acc = 0.f;
      for (int k4 = 0; k4 < (Hn >> 2); k4 += 4) {
#pragma unroll
        for (int u = 0; u < 4; ++u) {
          const float4 w = wp[(size_t)(k4 + u) * Vn];
          fma4(acc, w, xr[k4 + u]);
        }
      }
      l = acc + fcb[v];
    }
    if (v == tgv[rr]) lgt[rr] = l;  // target logit for the loss
    // wave-level argmax (first-max tie-break), 4 waves per row
    {
      float m = l;
      int mi = v;
#pragma unroll
      for (int off = 32; off; off >>= 1) {
        const float om = __shfl_xor(m, off);
        const int oi = __shfl_xor(mi, off);
        if (om > m || (om == m && oi < mi)) { m = om; mi = oi; }
      }
      if ((tid & 63) == 0) {
        wred[tid >> 6] = m;
        wredi[tid >> 6] = mi;
      }
    }
    __syncthreads();  // B9
    int am_r = 0;  // valid only in tid<4
    if (tid < 4) {
      float bm = wred[4 * tid];
      int bi = wredi[4 * tid];
#pragma unroll
      for (int q = 1; q < 4; ++q) {
        const float o = wred[4 * tid + q];
        const int oi = wredi[4 * tid + q];
        if (o > bm || (o == bm && oi < bi)) { bm = o; bi = oi; }
      }
      mxv[tid] = bm;
      am_r = bi;
    }
    __syncthreads();  // B10
    {
      float ex = expf(l - mxv[rr]);
#pragma unroll
      for (int off = 32; off; off >>= 1) ex += __shfl_xor(ex, off);
      if ((tid & 63) == 0) wred[tid >> 6] = ex;
    }
    __syncthreads();  // B11
    if (tid < 4) {
      tokb[tid] = am_r;
      if (am_r != tgv[tid]) mfs[tid] = 0;
      out[(size_t)(b0 + tid) * Tn + t] = (float)am_r;
    }
    if (tid == 0) {
#pragma unroll
      for (int r = 0; r < 4; ++r) {
        const float s = wred[4 * r] + wred[4 * r + 1] + wred[4 * r + 2] + wred[4 * r + 3];
        run_loss += -(lgt[r] - mxv[r] - logf(s)) * (1.f / 1024.f);
      }
    }
    // no trailing barrier needed: next-step hazards are covered by B1..B11
  }

  __syncthreads();
  if (tid == 0) {
    atomicAdd(wsloss, run_loss);
    atomicAdd(wscorrect, mfs[0] + mfs[1] + mfs[2] + mfs[3]);
  }
}

// ============ Path A fallback: R5-verified decoder (uncoalesced weights) ========
__device__ __forceinline__ void gru_layer4(int j, const float* __restrict__ x,
                                           int xstride, int K,
                                           float* __restrict__ h,
                                           const float* __restrict__ Wih,
                                           const float* __restrict__ Whh,
                                           const float* __restrict__ bih,
                                           const float* __restrict__ bhh) {
  float ai0[4] = {}, ai1[4] = {}, ai2[4] = {};
  {
    const float4* w0 = (const float4*)(Wih + (size_t)j * K);
    const float4* w1 = (const float4*)(Wih + (size_t)(j + 512) * K);
    const float4* w2 = (const float4*)(Wih + (size_t)(j + 1024) * K);
    for (int i = 0; i < K / 4; ++i) {
      const float4 a = w0[i], b = w1[i], c = w2[i];
#pragma unroll
      for (int r = 0; r < 4; ++r) {
        const float4 xv = ((const float4*)(x + r * xstride))[i];
        fma4(ai0[r], a, xv); fma4(ai1[r], b, xv); fma4(ai2[r], c, xv);
      }
    }
  }
  float ah0[4] = {}, ah1[4] = {}, ah2[4] = {};
  {
    const float4* w0 = (const float4*)(Whh + (size_t)j * Hn);
    const float4* w1 = (const float4*)(Whh + (size_t)(j + 512) * Hn);
    const float4* w2 = (const float4*)(Whh + (size_t)(j + 1024) * Hn);
    for (int i = 0; i < Hn / 4; ++i) {
      const float4 a = w0[i], b = w1[i], c = w2[i];
#pragma unroll
      for (int r = 0; r < 4; ++r) {
        const float4 xv = ((const float4*)(h + r * Hn))[i];
        fma4(ah0[r], a, xv); fma4(ah1[r], b, xv); fma4(ah2[r], c, xv);
      }
    }
  }
  const float bi0 = bih[j], bi1 = bih[j + 512], bi2 = bih[j + 1024];
  const float bh0 = bhh[j], bh1 = bhh[j + 512], bh2 = bhh[j + 1024];
  float hn[4];
#pragma unroll
  for (int r = 0; r < 4; ++r) {
    const float ir = ai0[r] + bi0, iz = ai1[r] + bi1, in_ = ai2[r] + bi2;
    const float hr = ah0[r] + bh0, hz = ah1[r] + bh1, hnn = ah2[r] + bh2;
    const float rg = 1.f / (1.f + expf(-(ir + hr)));
    const float zg = 1.f / (1.f + expf(-(iz + hz)));
    const float ng = tanhf(in_ + rg * hnn);
    hn[r] = (1.f - zg) * ng + zg * h[r * Hn + j];
  }
  __syncthreads();
#pragma unroll
  for (int r = 0; r < 4; ++r) h[r * Hn + j] = hn[r];
  __syncthreads();
}

__global__ __launch_bounds__(512, 1) void decoder_r4(
    const float* __restrict__ state, const float* __restrict__ enc,
    const int* __restrict__ target, const float* __restrict__ emb,
    const float* __restrict__ Wa, const float* __restrict__ bWa,
    const float* __restrict__ Va, const float* __restrict__ bVa,
    const float* __restrict__ Wih0, const float* __restrict__ Whh0,
    const float* __restrict__ bih0, const float* __restrict__ bhh0,
    const float* __restrict__ Wih1, const float* __restrict__ Whh1,
    const float* __restrict__ bih1, const float* __restrict__ bhh1,
    const float* __restrict__ fcW, const float* __restrict__ fcb,
    const float* __restrict__ kproj, float* __restrict__ out,
    float* __restrict__ wsloss, int* __restrict__ wscorrect) {
  __shared__ float h0s[4 * Hn], h1s[4 * Hn], qps[4 * Hn], gins[4 * EHn], vas[Hn];
  __shared__ float red[1024], lg[1024];
  __shared__ int ridx[1024];
  __shared__ float wrs[4 * Sn];
  __shared__ float mxv[4], lzv[4], llv[4];
  __shared__ int amv[4], tgv[4], tokb[4], mfs[4];

  const int tid = threadIdx.x;
  const int b0 = blockIdx.x * 4;

  for (int i = tid; i < 4 * Hn; i += 512) {
    const int r = i >> 9, j = i & 511;
    h0s[i] = state[(size_t)(b0 + r) * Hn + j];
    h1s[i] = state[(size_t)(Bn + b0 + r) * Hn + j];
  }
  vas[tid] = Va[tid];
  if (tid < 4) { tokb[tid] = 1; mfs[tid] = 1; llv[tid] = 0.f; }
  __syncthreads();

  float run_loss = 0.f;

  for (int t = 0; t < Tn; ++t) {
    {
      const int h = tid;
      const float4* w4 = (const float4*)(Wa + (size_t)h * Hn);
      float a0 = 0.f, a1 = 0.f, a2 = 0.f, a3 = 0.f;
      for (int i = 0; i < Hn / 4; ++i) {
        const float4 w = w4[i];
        const float4 x0 = ((const float4*)(h1s))[i];
        const float4 x1 = ((const float4*)(h1s + Hn))[i];
        const float4 x2 = ((const float4*)(h1s + 2 * Hn))[i];
        const float4 x3 = ((const float4*)(h1s + 3 * Hn))[i];
        fma4(a0, w, x0); fma4(a1, w, x1); fma4(a2, w, x2); fma4(a3, w, x3);
      }
      const float bb = bWa[h];
      qps[h] = a0 + bb; qps[Hn + h] = a1 + bb;
      qps[2 * Hn + h] = a2 + bb; qps[3 * Hn + h] = a3 + bb;
    }
    __syncthreads();
    {
      const int p = tid >> 2, q = tid & 3;
      const int r = p >> 5, s = p & 31;
      const float4* kp4 = (const float4*)(kproj + ((size_t)s * Bn + (b0 + r)) * Hn);
      const float4* qp4 = (const float4*)(qps + r * Hn);
      const float4* va4 = (const float4*)vas;
      float partial = 0.f;
      for (int i = 0; i < 32; ++i) {
        const int f = q + (i << 2);
        const float4 k4 = kp4[f], q4 = qp4[f], v4 = va4[f];
        partial += v4.x * tanhf(q4.x + k4.x);
        partial += v4.y * tanhf(q4.y + k4.y);
        partial += v4.z * tanhf(q4.z + k4.z);
        partial += v4.w * tanhf(q4.w + k4.w);
      }
      red[tid] = partial;
    }
    __syncthreads();
    if (tid < 128) {
      float e = red[tid * 4] + red[tid * 4 + 1] + red[tid * 4 + 2] + red[tid * 4 + 3] + bVa[0];
      float m = e;
#pragma unroll
      for (int off = 16; off; off >>= 1) m = fmaxf(m, __shfl_xor(m, off));
      const float ex = expf(e - m);
      float ss = ex;
#pragma unroll
      for (int off = 16; off; off >>= 1) ss += __shfl_xor(ss, off);
      const float w = ex / ss;
      const int r = tid >> 5, s = tid & 31;
      wrs[tid] = w;
      out[(size_t)(Bn * Tn) + (size_t)t * (Bn * Sn) + (size_t)(b0 + r) * Sn + s] = w;
    }
    __syncthreads();
    {
      const int h = tid;
      float c0 = 0.f, c1 = 0.f, c2 = 0.f, c3 = 0.f;
      for (int s = 0; s < Sn; ++s) {
        const size_t base = ((size_t)s * Bn + b0) * Hn + h;
        c0 = fmaf(wrs[s], enc[base], c0);
        c1 = fmaf(wrs[32 + s], enc[base + Hn], c1);
        c2 = fmaf(wrs[64 + s], enc[base + 2 * Hn], c2);
        c3 = fmaf(wrs[96 + s], enc[base + 3 * Hn], c3);
      }
      gins[En + h] = c0; gins[EHn + En + h] = c1;
      gins[2 * EHn + En + h] = c2; gins[3 * EHn + En + h] = c3;
    }
    for (int i = tid; i < 4 * En; i += 512) {
      const int r = i >> 8, j = i & 255;
      gins[r * EHn + j] = fmaxf(emb[(size_t)tokb[r] * En + j], 0.f);
    }
    __syncthreads();
    gru_layer4(tid, gins, EHn, EHn, h0s, Wih0, Whh0, bih0, bhh0);
    gru_layer4(tid, h0s, Hn, Hn, h1s, Wih1, Whh1, bih1, bhh1);
    {
      const int v = tid & 255;
      const int rA = tid >> 8, rB = rA + 2;
      const float4* w4 = (const float4*)(fcW + (size_t)v * Hn);
      const float4* xA = (const float4*)(h1s + rA * Hn);
      const float4* xB = (const float4*)(h1s + rB * Hn);
      float aA = 0.f, aB = 0.f;
      for (int i = 0; i < Hn / 4; ++i) {
        const float4 w = w4[i];
        const float4 a = xA[i], b = xB[i];
        fma4(aA, w, a); fma4(aB, w, b);
      }
      const float fb = fcb[v];
      const float lA = aA + fb, lB = aB + fb;
      lg[rA * 256 + v] = lA; red[rA * 256 + v] = lA; ridx[rA * 256 + v] = v;
      lg[rB * 256 + v] = lB; red[rB * 256 + v] = lB; ridx[rB * 256 + v] = v;
    }
    __syncthreads();
    for (int off = 128; off; off >>= 1) {
#pragma unroll
      for (int half = 0; half < 2; ++half) {
        const int u = tid + half * 512;
        if ((u & 255) < off) {
          const int u2 = u + off;
          const float o = red[u2]; const int oi = ridx[u2];
          if (o > red[u] || (o == red[u] && oi < ridx[u])) { red[u] = o; ridx[u] = oi; }
        }
      }
      __syncthreads();
    }
    if (tid < 4) {
      mxv[tid] = red[tid * 256];
      amv[tid] = ridx[tid * 256];
      tgv[tid] = target[(size_t)(b0 + tid) * Tn + t];
    }
    __syncthreads();
#pragma unroll
    for (int half = 0; half < 2; ++half) {
      const int u = tid + half * 512;
      red[u] = expf(lg[u] - mxv[u >> 8]);
    }
    __syncthreads();
    for (int off = 128; off; off >>= 1) {
#pragma unroll
      for (int half = 0; half < 2; ++half) {
        const int u = tid + half * 512;
        if ((u & 255) < off) red[u] += red[u + off];
      }
      __syncthreads();
    }
    if (tid < 4) {
      const int r = tid;
      lzv[r] = logf(red[r * 256]);
      tokb[r] = amv[r];
      if (amv[r] != tgv[r]) mfs[r] = 0;
      out[(size_t)(b0 + r) * Tn + t] = (float)amv[r];
    }
    __syncthreads();
#pragma unroll
    for (int half = 0; half < 2; ++half) {
      const int u = tid + half * 512;
      const int r = u >> 8, v = u & 255;
      if (v == tgv[r]) llv[r] = -(lg[u] - mxv[r] - lzv[r]) * (1.f / 1024.f);
    }
    __syncthreads();
    if (tid == 0) run_loss += llv[0] + llv[1] + llv[2] + llv[3];
    __syncthreads();
  }

  if (tid == 0) {
    atomicAdd(wsloss, run_loss);
    atomicAdd(wscorrect, mfs[0] + mfs[1] + mfs[2] + mfs[3]);
  }
}

// ============ common epilogue ============
__global__ void ws_init(float* wsloss, int* wscorrect) {
  wsloss[0] = 0.f;
  wscorrect[0] = 0;
}

__global__ void finisher(const float* __restrict__ wsloss,
                         const int* __restrict__ wscorrect, float* __restrict__ out) {
  const size_t base = (size_t)Bn * Tn + (size_t)Tn * Bn * Sn;
  out[base] = wsloss[0];
  out[base + 1] = (float)wscorrect[0];
}

extern "C" void kernel_launch(void* const* d_in, const int* in_sizes, int n_in,
                              void* d_out, int out_size, void* d_ws, size_t ws_size,
                              hipStream_t stream) {
  const float* state = (const float*)d_in[0];
  const float* enc = (const float*)d_in[1];
  const int* target = (const int*)d_in[2];
  const float* emb = (const float*)d_in[3];
  const float* Wa = (const float*)d_in[4];
  const float* bWa = (const float*)d_in[5];
  const float* Ua = (const float*)d_in[6];
  const float* bUa = (const float*)d_in[7];
  const float* Va = (const float*)d_in[8];
  const float* bVa = (const float*)d_in[9];
  const float* Wih0 = (const float*)d_in[10];
  const float* Whh0 = (const float*)d_in[11];
  const float* bih0 = (const float*)d_in[12];
  const float* bhh0 = (const float*)d_in[13];
  const float* Wih1 = (const float*)d_in[14];
  const float* Whh1 = (const float*)d_in[15];
  const float* bih1 = (const float*)d_in[16];
  const float* bhh1 = (const float*)d_in[17];
  const float* fcW = (const float*)d_in[18];
  const float* fcb = (const float*)d_in[19];
  float* out = (float*)d_out;

  const size_t KPROJ_FLOATS = (size_t)Sn * Bn * Hn;  // 64 MB

  const size_t N0IH = (size_t)G3 * (EHn / 4);
  const size_t NHH = (size_t)G3 * (Hn / 4);
  const size_t NWA = (size_t)Hn * (Hn / 4);
  const size_t NFC = (size_t)Vn * (Hn / 4);
  const size_t WT_TOTAL = N0IH + 3 * NHH + NWA + NFC;  // 15 MB
  const size_t NEED_A2 = WT_TOTAL * 16 + KPROJ_FLOATS * 4 + 256;

  if (ws_size >= NEED_A2) {
    float4* W0ihT = (float4*)d_ws;
    float4* W0hhT = W0ihT + N0IH;
    float4* W1ihT = W0hhT + NHH;
    float4* W1hhT = W1ihT + NHH;
    float4* WaT = W1hhT + NHH;
    float4* fcWT = WaT + NWA;
    float* kproj = (float*)(fcWT + NFC);
    float* wsloss = kproj + KPROJ_FLOATS;
    int* wscorrect = (int*)(wsloss + 1);

    ws_init<<<1, 1, 0, stream>>>(wsloss, wscorrect);
    transpose_pack<<<(int)((N0IH + 255) / 256), 256, 0, stream>>>(Wih0, W0ihT, G3, EHn);
    transpose_pack<<<(int)((NHH + 255) / 256), 256, 0, stream>>>(Whh0, W0hhT, G3, Hn);
    transpose_pack<<<(int)((NHH + 255) / 256), 256, 0, stream>>>(Wih1, W1ihT, G3, Hn);
    transpose_pack<<<(int)((NHH + 255) / 256), 256, 0, stream>>>(Whh1, W1hhT, G3, Hn);
    transpose_pack<<<(int)((NWA + 255) / 256), 256, 0, stream>>>(Wa, WaT, Hn, Hn);
    transpose_pack<<<(int)((NFC + 255) / 256), 256, 0, stream>>>(fcW, fcWT, Vn, Hn);
    gemm_bias<<<dim3(Hn / 64, (Sn * Bn) / 64), 256, 0, stream>>>(
        enc, Ua, bUa, kproj, Sn * Bn, Hn, Hn);
    decoder_r4y<<<Bn / 4, 1024, 0, stream>>>(
        state, enc, target, emb, WaT, bWa, Va, bVa, W0ihT, W0hhT, bih0, bhh0,
        W1ihT, W1hhT, bih1, bhh1, fcWT, fcb, kproj, out, wsloss, wscorrect);
    finisher<<<1, 1, 0, stream>>>(wsloss, wscorrect, out);
  } else {
    float* kproj = (float*)d_ws;
    float* wsloss = (float*)d_ws + KPROJ_FLOATS;
    int* wscorrect = (int*)((float*)d_ws + KPROJ_FLOATS + 1);
    ws_init<<<1, 1, 0, stream>>>(wsloss, wscorrect);
    gemm_bias<<<dim3(Hn / 64, (Sn * Bn) / 64), 256, 0, stream>>>(
        enc, Ua, bUa, kproj, Sn * Bn, Hn, Hn);
    decoder_r4<<<Bn / 4, 512, 0, stream>>>(
        state, enc, target, emb, Wa, bWa, Va, bVa, Wih0, Whh0, bih0, bhh0,
        Wih1, Whh1, bih1, bhh1, fcW, fcb, kproj, out, wsloss, wscorrect);
    finisher<<<1, 1, 0, stream>>>(wsloss, wscorrect, out);
  }
}